// Round 3
// baseline (690.840 us; speedup 1.0000x reference)
//
#include <hip/hip_runtime.h>
#include <cmath>

typedef __attribute__((ext_vector_type(4))) float f32x4;
typedef __attribute__((ext_vector_type(8))) short s16x8;
typedef __attribute__((ext_vector_type(4))) unsigned short u16x4;

static constexpr int NROW = 64;     // K
static constexpr int NCOL = 512;    // L
static constexpr int NBATCH = 1024; // 32*32

__device__ inline unsigned short f32_to_bf16_rne(float f) {
  unsigned u = __builtin_bit_cast(unsigned, f);
  unsigned r = (u + 0x7FFFu + ((u >> 16) & 1u)) >> 16;
  return (unsigned short)r;
}
__device__ inline float bf16_to_f32(unsigned short h) {
  unsigned u = ((unsigned)h) << 16;
  return __builtin_bit_cast(float, u);
}

// Kernel 1: per-batch G = X X^T via bf16 hi/lo split MFMA
// (G ~= Xh Xh^T + Xh Xl^T + Xl Xh^T), then 64x64 LDL recurrence
//   W[i][k] = G[i][k] - sum_{m<k} (W[k][m]/W[m][m]) * W[i][m].
// Emits c[i][m] = W[i][m]/W[m][m] for m<i (0 elsewhere) + 1/sqrt(W[i][i])
// into the batch's own output slot (scratch; overwritten by kernel 2).
__global__ __launch_bounds__(256, 4) void gs_gram_kernel(const float* __restrict__ x,
                                                         float* __restrict__ outbuf)
{
  __shared__ unsigned short Hs[64][72];  // hi bf16 chunk, +8 pad
  __shared__ unsigned short Ls[64][72];  // lo bf16 chunk
  __shared__ float GW[64][68];           // G then W in place
  __shared__ float invn[64];

  const int b = blockIdx.x;
  const int t = threadIdx.x;
  const int lane = t & 63;
  const int w = t >> 6;                  // wave id = output tile-row

  const float* __restrict__ X = x + (size_t)b * (NROW * NCOL);

  f32x4 acc[4];
#pragma unroll
  for (int j = 0; j < 4; ++j) { acc[j][0] = 0.f; acc[j][1] = 0.f; acc[j][2] = 0.f; acc[j][3] = 0.f; }

  const int lrow = t >> 4;               // 0..15, staging row base
  const int lcol = (t & 15) * 4;         // staging col (floats)
  const int frow = lane & 15;            // MFMA frag row within tile
  const int fk   = (lane >> 4) * 8;      // MFMA frag k offset within 32-step

  for (int ch = 0; ch < 8; ++ch) {
    __syncthreads();                     // protect Hs/Ls reuse
    // stage 64x64 f32 chunk as bf16 hi/lo, 256B-contiguous global segments
#pragma unroll
    for (int p = 0; p < 4; ++p) {
      const int r = lrow + 16 * p;
      const f32x4 v = *(const f32x4*)(X + (size_t)r * NCOL + ch * 64 + lcol);
      u16x4 hv, lv;
#pragma unroll
      for (int j = 0; j < 4; ++j) {
        const float f = v[j];
        const unsigned short h = f32_to_bf16_rne(f);
        const unsigned short l = f32_to_bf16_rne(f - bf16_to_f32(h));
        hv[j] = h; lv[j] = l;
      }
      *(u16x4*)&Hs[r][lcol] = hv;
      *(u16x4*)&Ls[r][lcol] = lv;
    }
    __syncthreads();
    // two 32-wide k-steps of MFMA; wave w computes G tiles (w, 0..3)
#pragma unroll
    for (int s = 0; s < 2; ++s) {
      const int kc = s * 32 + fk;
      const s16x8 ha = *(const s16x8*)&Hs[16 * w + frow][kc];
      const s16x8 la = *(const s16x8*)&Ls[16 * w + frow][kc];
#pragma unroll
      for (int bt = 0; bt < 4; ++bt) {
        const s16x8 hb = *(const s16x8*)&Hs[16 * bt + frow][kc];
        const s16x8 lb = *(const s16x8*)&Ls[16 * bt + frow][kc];
        acc[bt] = __builtin_amdgcn_mfma_f32_16x16x32_bf16(ha, hb, acc[bt], 0, 0, 0);
        acc[bt] = __builtin_amdgcn_mfma_f32_16x16x32_bf16(ha, lb, acc[bt], 0, 0, 0);
        acc[bt] = __builtin_amdgcn_mfma_f32_16x16x32_bf16(la, hb, acc[bt], 0, 0, 0);
      }
    }
  }

  // C/D layout (verified m89): col = lane&15, row = (lane>>4)*4 + reg
  const int drow = (lane >> 4) * 4;
  const int dcol = lane & 15;
#pragma unroll
  for (int bt = 0; bt < 4; ++bt)
#pragma unroll
    for (int rr = 0; rr < 4; ++rr)
      GW[16 * w + drow + rr][16 * bt + dcol] = acc[bt][rr];
  __syncthreads();

  // LDL recurrence, wave 0, lane = row i; float4 over m (4 indep accumulators)
  if (t < 64) {
    const int i = t;
    for (int k = 0; k < 64; ++k) {
      float wv = GW[i][k];
      f32x4 s4; s4[0] = 0.f; s4[1] = 0.f; s4[2] = 0.f; s4[3] = 0.f;
      int m = 0;
      for (; m + 4 <= k; m += 4) {
        const f32x4 ck = *(const f32x4*)&GW[k][m];   // uniform broadcast
        const f32x4 iv = *(const f32x4*)&invn[m];    // uniform broadcast
        const f32x4 wi = *(const f32x4*)&GW[i][m];   // per-lane
        s4 += ck * iv * wi;
      }
      float s = s4[0] + s4[1] + s4[2] + s4[3];
      for (; m < k; ++m) s += GW[k][m] * invn[m] * GW[i][m];
      wv -= s;
      GW[i][k] = wv;
      if (i == k) invn[k] = 1.0f / wv;
    }
  }
  __syncthreads();

  // emit zero-padded coefficient matrix + inv norms
  float* __restrict__ slot = outbuf + (size_t)b * (NROW * NCOL);
#pragma unroll
  for (int q = 0; q < 16; ++q) {
    const int idx = t + 256 * q;
    const int ii = idx >> 6;
    const int mm = idx & 63;
    slot[idx] = (mm < ii) ? GW[ii][mm] * invn[mm] : 0.0f;
  }
  if (t < 64) slot[4096 + t] = 1.0f / sqrtf(GW[t][t]);
}

// Kernel 2: forward substitution q_i = x_i - sum_{m<i} c[i][m] q_m + row
// normalization.  Thread t owns columns 2t,2t+1 of all 64 rows in registers;
// coefficients via uniform float4 LDS broadcasts (zero-padded upper).
__global__ __launch_bounds__(256, 2) void gs_apply_kernel(const float* __restrict__ x,
                                                          float* __restrict__ outbuf)
{
  __shared__ float cL[64 * 64];
  __shared__ float sL[64];

  const int b = blockIdx.x;
  const int t = threadIdx.x;
  float* __restrict__ slot = outbuf + (size_t)b * (NROW * NCOL);

  // pull this batch's coefficients into LDS BEFORE any output store
#pragma unroll
  for (int q = 0; q < 16; ++q) cL[t + 256 * q] = slot[t + 256 * q];
  if (t < 64) sL[t] = slot[4096 + t];
  __syncthreads();

  const float* __restrict__ X = x + (size_t)b * (NROW * NCOL);
  float ax[64], ay[64];
#pragma unroll
  for (int rr = 0; rr < 64; ++rr) {
    const float2 v = *(const float2*)(X + (size_t)rr * NCOL + 2 * t);
    ax[rr] = v.x; ay[rr] = v.y;
  }

  // triangular solve, float4 coefficient groups (c[i][m]=0 for m>=i)
#pragma unroll
  for (int i = 1; i < 64; ++i) {
#pragma unroll
    for (int m4 = 0; m4 < 16; ++m4) {
      if (m4 * 4 < i) {
        const f32x4 c4 = *(const f32x4*)&cL[i * 64 + 4 * m4];
        ax[i] -= c4[0] * ax[4 * m4 + 0] + c4[1] * ax[4 * m4 + 1]
               + c4[2] * ax[4 * m4 + 2] + c4[3] * ax[4 * m4 + 3];
        ay[i] -= c4[0] * ay[4 * m4 + 0] + c4[1] * ay[4 * m4 + 1]
               + c4[2] * ay[4 * m4 + 2] + c4[3] * ay[4 * m4 + 3];
      }
    }
  }

#pragma unroll
  for (int rr = 0; rr < 64; ++rr) {
    const float s = sL[rr];
    float2 v;
    v.x = ax[rr] * s;
    v.y = ay[rr] * s;
    *(float2*)(slot + (size_t)rr * NCOL + 2 * t) = v;
  }
}

extern "C" void kernel_launch(void* const* d_in, const int* in_sizes, int n_in,
                              void* d_out, int out_size, void* d_ws, size_t ws_size,
                              hipStream_t stream) {
  const float* x = (const float*)d_in[0];
  float* out = (float*)d_out;
  gs_gram_kernel<<<NBATCH, 256, 0, stream>>>(x, out);
  gs_apply_kernel<<<NBATCH, 256, 0, stream>>>(x, out);
}

// Round 5
// 291.559 us; speedup vs baseline: 2.3695x; 2.3695x over previous
//
#include <hip/hip_runtime.h>
#include <cmath>

typedef __attribute__((ext_vector_type(4))) float f32x4;
typedef __attribute__((ext_vector_type(8))) short s16x8;
typedef __attribute__((ext_vector_type(4))) unsigned short u16x4;

static constexpr int NROW = 64;     // K
static constexpr int NCOL = 512;    // L
static constexpr int NBATCH = 1024; // 32*32

__device__ inline unsigned short f32_to_bf16_rne(float f) {
  unsigned u = __builtin_bit_cast(unsigned, f);
  unsigned r = (u + 0x7FFFu + ((u >> 16) & 1u)) >> 16;
  return (unsigned short)r;
}
__device__ inline float bf16_to_f32(unsigned short h) {
  unsigned u = ((unsigned)h) << 16;
  return __builtin_bit_cast(float, u);
}

// Kernel 1: per-batch G = X X^T via bf16 hi/lo split MFMA
// (G ~= Xh Xh^T + Xh Xl^T + Xl Xh^T), then 64x64 LDL recurrence
//   W[i][k] = G[i][k] - sum_{m<k} (W[k][m]/W[m][m]) * W[i][m].
// Emits c[i][m] = W[i][m]/W[m][m] for m<i (0 elsewhere) + 1/sqrt(W[i][i])
// into the batch's own output slot (scratch; overwritten by kernel 2).
__global__ __launch_bounds__(256, 4) void gs_gram_kernel(const float* __restrict__ x,
                                                         float* __restrict__ outbuf)
{
  __shared__ unsigned short Hs[64][72];  // hi bf16 chunk, +8 pad
  __shared__ unsigned short Ls[64][72];  // lo bf16 chunk
  __shared__ float GW[64][68];           // G then W in place
  __shared__ float invn[64];

  const int b = blockIdx.x;
  const int t = threadIdx.x;
  const int lane = t & 63;
  const int w = t >> 6;                  // wave id = output tile-row

  const float* __restrict__ X = x + (size_t)b * (NROW * NCOL);

  f32x4 acc[4];
#pragma unroll
  for (int j = 0; j < 4; ++j) { acc[j][0] = 0.f; acc[j][1] = 0.f; acc[j][2] = 0.f; acc[j][3] = 0.f; }

  const int lrow = t >> 4;               // 0..15, staging row base
  const int lcol = (t & 15) * 4;         // staging col (floats)
  const int frow = lane & 15;            // MFMA frag row within tile
  const int fk   = (lane >> 4) * 8;      // MFMA frag k offset within 32-step

  for (int ch = 0; ch < 8; ++ch) {
    __syncthreads();                     // protect Hs/Ls reuse
    // stage 64x64 f32 chunk as bf16 hi/lo, 256B-contiguous global segments
#pragma unroll
    for (int p = 0; p < 4; ++p) {
      const int r = lrow + 16 * p;
      const f32x4 v = *(const f32x4*)(X + (size_t)r * NCOL + ch * 64 + lcol);
      u16x4 hv, lv;
#pragma unroll
      for (int j = 0; j < 4; ++j) {
        const float f = v[j];
        const unsigned short h = f32_to_bf16_rne(f);
        const unsigned short l = f32_to_bf16_rne(f - bf16_to_f32(h));
        hv[j] = h; lv[j] = l;
      }
      *(u16x4*)&Hs[r][lcol] = hv;
      *(u16x4*)&Ls[r][lcol] = lv;
    }
    __syncthreads();
    // two 32-wide k-steps of MFMA; wave w computes G tiles (w, 0..3)
#pragma unroll
    for (int s = 0; s < 2; ++s) {
      const int kc = s * 32 + fk;
      const s16x8 ha = *(const s16x8*)&Hs[16 * w + frow][kc];
      const s16x8 la = *(const s16x8*)&Ls[16 * w + frow][kc];
#pragma unroll
      for (int bt = 0; bt < 4; ++bt) {
        const s16x8 hb = *(const s16x8*)&Hs[16 * bt + frow][kc];
        const s16x8 lb = *(const s16x8*)&Ls[16 * bt + frow][kc];
        acc[bt] = __builtin_amdgcn_mfma_f32_16x16x32_bf16(ha, hb, acc[bt], 0, 0, 0);
        acc[bt] = __builtin_amdgcn_mfma_f32_16x16x32_bf16(ha, lb, acc[bt], 0, 0, 0);
        acc[bt] = __builtin_amdgcn_mfma_f32_16x16x32_bf16(la, hb, acc[bt], 0, 0, 0);
      }
    }
  }

  // C/D layout (verified m89): col = lane&15, row = (lane>>4)*4 + reg
  const int drow = (lane >> 4) * 4;
  const int dcol = lane & 15;
#pragma unroll
  for (int bt = 0; bt < 4; ++bt)
#pragma unroll
    for (int rr = 0; rr < 4; ++rr)
      GW[16 * w + drow + rr][16 * bt + dcol] = acc[bt][rr];
  __syncthreads();

  // LDL recurrence, wave 0, lane = row i; float4 over m (4 indep accumulators)
  if (t < 64) {
    const int i = t;
    for (int k = 0; k < 64; ++k) {
      float wv = GW[i][k];
      f32x4 s4; s4[0] = 0.f; s4[1] = 0.f; s4[2] = 0.f; s4[3] = 0.f;
      int m = 0;
      for (; m + 4 <= k; m += 4) {
        const f32x4 ck = *(const f32x4*)&GW[k][m];   // uniform broadcast
        const f32x4 iv = *(const f32x4*)&invn[m];    // uniform broadcast
        const f32x4 wi = *(const f32x4*)&GW[i][m];   // per-lane
        s4 += ck * iv * wi;
      }
      float s = s4[0] + s4[1] + s4[2] + s4[3];
      for (; m < k; ++m) s += GW[k][m] * invn[m] * GW[i][m];
      wv -= s;
      GW[i][k] = wv;
      if (i == k) invn[k] = 1.0f / wv;
    }
  }
  __syncthreads();

  // emit zero-padded coefficient matrix + inv norms
  float* __restrict__ slot = outbuf + (size_t)b * (NROW * NCOL);
#pragma unroll
  for (int q = 0; q < 16; ++q) {
    const int idx = t + 256 * q;
    const int ii = idx >> 6;
    const int mm = idx & 63;
    slot[idx] = (mm < ii) ? GW[ii][mm] * invn[mm] : 0.0f;
  }
  if (t < 64) slot[4096 + t] = 1.0f / sqrtf(GW[t][t]);
}

// Kernel 2: forward substitution q_i = x_i - sum_{m<i} c[i][m] q_m + row
// normalization.  Thread t owns columns 2t,2t+1 of all 64 rows in registers.
// Coefficients: uniform float2 LDS broadcasts with ROUND-UP trip count —
// the overshoot term multiplies the zero-padded c[i][i]=0, so no branch in
// the body (keeps the nest fully unrollable -> arrays stay in VGPRs).
__global__ __launch_bounds__(256) void gs_apply_kernel(const float* __restrict__ x,
                                                       float* __restrict__ outbuf)
{
  __shared__ float cL[64 * 64];
  __shared__ float sL[64];

  const int b = blockIdx.x;
  const int t = threadIdx.x;
  float* __restrict__ slot = outbuf + (size_t)b * (NROW * NCOL);

  // pull this batch's coefficients into LDS BEFORE any output store
#pragma unroll
  for (int q = 0; q < 16; ++q) cL[t + 256 * q] = slot[t + 256 * q];
  if (t < 64) sL[t] = slot[4096 + t];
  __syncthreads();

  const float* __restrict__ X = x + (size_t)b * (NROW * NCOL);
  float ax[64], ay[64];
#pragma unroll
  for (int rr = 0; rr < 64; ++rr) {
    const float2 v = *(const float2*)(X + (size_t)rr * NCOL + 2 * t);
    ax[rr] = v.x; ay[rr] = v.y;
  }

  // fully-unrolled triangular solve, float2 coefficient groups
#pragma unroll
  for (int i = 1; i < 64; ++i) {
#pragma unroll
    for (int m2 = 0; m2 < (i + 1) / 2; ++m2) {
      const float2 c2 = *(const float2*)&cL[i * 64 + 2 * m2];
      ax[i] -= c2.x * ax[2 * m2] + c2.y * ax[2 * m2 + 1];
      ay[i] -= c2.x * ay[2 * m2] + c2.y * ay[2 * m2 + 1];
    }
  }

#pragma unroll
  for (int rr = 0; rr < 64; ++rr) {
    const float s = sL[rr];
    float2 v;
    v.x = ax[rr] * s;
    v.y = ay[rr] * s;
    *(float2*)(slot + (size_t)rr * NCOL + 2 * t) = v;
  }
}

extern "C" void kernel_launch(void* const* d_in, const int* in_sizes, int n_in,
                              void* d_out, int out_size, void* d_ws, size_t ws_size,
                              hipStream_t stream) {
  const float* x = (const float*)d_in[0];
  float* out = (float*)d_out;
  gs_gram_kernel<<<NBATCH, 256, 0, stream>>>(x, out);
  gs_apply_kernel<<<NBATCH, 256, 0, stream>>>(x, out);
}

// Round 6
// 167.016 us; speedup vs baseline: 4.1364x; 1.7457x over previous
//
#include <hip/hip_runtime.h>
#include <cmath>

typedef __attribute__((ext_vector_type(4))) float f32x4;
typedef __attribute__((ext_vector_type(8))) short s16x8;
typedef __attribute__((ext_vector_type(4))) short s16x4;
typedef __attribute__((ext_vector_type(4))) unsigned short u16x4;

static constexpr int NROW = 64;     // K
static constexpr int NCOL = 512;    // L
static constexpr int NBATCH = 1024; // 32*32

__device__ inline unsigned short f32_to_bf16_rne(float f) {
  unsigned u = __builtin_bit_cast(unsigned, f);
  unsigned r = (u + 0x7FFFu + ((u >> 16) & 1u)) >> 16;
  return (unsigned short)r;
}
__device__ inline float bf16_to_f32(unsigned short h) {
  unsigned u = ((unsigned)h) << 16;
  return __builtin_bit_cast(float, u);
}

// 8B-aligned s16x8 load (rows of XT are only 8B-aligned at stride 68)
__device__ inline s16x8 ld8(const unsigned short* p) {
  const s16x4 a = *(const s16x4*)(p);
  const s16x4 b = *(const s16x4*)(p + 4);
  s16x8 r;
  r[0]=a[0]; r[1]=a[1]; r[2]=a[2]; r[3]=a[3];
  r[4]=b[0]; r[5]=b[1]; r[6]=b[2]; r[7]=b[3];
  return r;
}

union StageTI {
  struct { unsigned short Hs[64][72]; unsigned short Ls[64][72]; } st;
  float TI[64][72];   // overlays Hs/Ls after the gram MFMA phase (both 18432 B)
};

// Kernel 1: G = X X^T (bf16 hi/lo MFMA) -> LDL recurrence -> explicit
// triangular inverse T = (I+Lc)^{-1} -> emit S*T as bf16 hi/lo into the
// batch's own output slot (scratch; fully overwritten by kernel 2).
__global__ __launch_bounds__(256, 4) void gs_gram_kernel(const float* __restrict__ x,
                                                         float* __restrict__ outbuf)
{
  __shared__ StageTI U;
  __shared__ float GW[64][68];   // G -> W -> Cs in place
  __shared__ float invn[64];
  __shared__ float isn[64];

  const int b = blockIdx.x;
  const int t = threadIdx.x;
  const int lane = t & 63;
  const int w = t >> 6;                  // wave id = output tile-row

  const float* __restrict__ X = x + (size_t)b * (NROW * NCOL);

  f32x4 acc[4];
#pragma unroll
  for (int j = 0; j < 4; ++j) { acc[j][0] = 0.f; acc[j][1] = 0.f; acc[j][2] = 0.f; acc[j][3] = 0.f; }

  const int lrow = t >> 4;               // 0..15, staging row base
  const int lcol = (t & 15) * 4;         // staging col (floats)
  const int frow = lane & 15;            // MFMA frag row within tile
  const int fk   = (lane >> 4) * 8;      // MFMA frag k offset within 32-step

  for (int ch = 0; ch < 8; ++ch) {
    __syncthreads();                     // protect Hs/Ls reuse
#pragma unroll
    for (int p = 0; p < 4; ++p) {
      const int r = lrow + 16 * p;
      const f32x4 v = *(const f32x4*)(X + (size_t)r * NCOL + ch * 64 + lcol);
      u16x4 hv, lv;
#pragma unroll
      for (int j = 0; j < 4; ++j) {
        const float f = v[j];
        const unsigned short h = f32_to_bf16_rne(f);
        const unsigned short l = f32_to_bf16_rne(f - bf16_to_f32(h));
        hv[j] = h; lv[j] = l;
      }
      *(u16x4*)&U.st.Hs[r][lcol] = hv;
      *(u16x4*)&U.st.Ls[r][lcol] = lv;
    }
    __syncthreads();
#pragma unroll
    for (int s = 0; s < 2; ++s) {
      const int kc = s * 32 + fk;
      const s16x8 ha = *(const s16x8*)&U.st.Hs[16 * w + frow][kc];
      const s16x8 la = *(const s16x8*)&U.st.Ls[16 * w + frow][kc];
#pragma unroll
      for (int bt = 0; bt < 4; ++bt) {
        const s16x8 hb = *(const s16x8*)&U.st.Hs[16 * bt + frow][kc];
        const s16x8 lb = *(const s16x8*)&U.st.Ls[16 * bt + frow][kc];
        acc[bt] = __builtin_amdgcn_mfma_f32_16x16x32_bf16(ha, hb, acc[bt], 0, 0, 0);
        acc[bt] = __builtin_amdgcn_mfma_f32_16x16x32_bf16(ha, lb, acc[bt], 0, 0, 0);
        acc[bt] = __builtin_amdgcn_mfma_f32_16x16x32_bf16(la, hb, acc[bt], 0, 0, 0);
      }
    }
  }

  // C/D layout: col = lane&15, row = (lane>>4)*4 + reg
  const int drow = (lane >> 4) * 4;
  const int dcol = lane & 15;
#pragma unroll
  for (int bt = 0; bt < 4; ++bt)
#pragma unroll
    for (int rr = 0; rr < 4; ++rr)
      GW[16 * w + drow + rr][16 * bt + dcol] = acc[bt][rr];
  __syncthreads();

  // LDL recurrence, wave 0, lane = row i
  if (t < 64) {
    const int i = t;
    for (int k = 0; k < 64; ++k) {
      float wv = GW[i][k];
      f32x4 s4; s4[0] = 0.f; s4[1] = 0.f; s4[2] = 0.f; s4[3] = 0.f;
      int m = 0;
      for (; m + 4 <= k; m += 4) {
        const f32x4 ck = *(const f32x4*)&GW[k][m];   // uniform broadcast
        const f32x4 iv = *(const f32x4*)&invn[m];    // uniform broadcast
        const f32x4 wi = *(const f32x4*)&GW[i][m];   // per-lane
        s4 += ck * iv * wi;
      }
      float s = s4[0] + s4[1] + s4[2] + s4[3];
      for (; m < k; ++m) s += GW[k][m] * invn[m] * GW[i][m];
      wv -= s;
      GW[i][k] = wv;
      if (i == k) invn[k] = 1.0f / wv;
    }
    isn[i] = sqrtf(invn[i]);             // 1/sqrt(n_i)
  }
  __syncthreads();

  // Cs[i][m] = W[i][m]/n_m for m<i, 0 elsewhere (in place, element-wise)
#pragma unroll
  for (int q = 0; q < 16; ++q) {
    const int idx = t + 256 * q;
    const int ii = idx >> 6;
    const int mm = idx & 63;
    const float v = (mm < ii) ? GW[ii][mm] * invn[mm] : 0.0f;
    GW[ii][mm] = v;
  }
  __syncthreads();

  // Triangular inverse TI = (I + Cs)^{-1}, wave 0, lane = column j.
  // Row recurrence: TI[i][j] = delta(i,j) - sum_{m<i} Cs[i][m]*TI[m][j].
  if (t < 64) {
    const int j = t;
    U.TI[0][j] = (j == 0) ? 1.0f : 0.0f;
    for (int i = 1; i < 64; ++i) {
      f32x4 s4; s4[0] = 0.f; s4[1] = 0.f; s4[2] = 0.f; s4[3] = 0.f;
      int m = 0;
      for (; m + 4 <= i; m += 4) {
        const f32x4 c4 = *(const f32x4*)&GW[i][m];   // uniform broadcast
        s4[0] += c4[0] * U.TI[m + 0][j];
        s4[1] += c4[1] * U.TI[m + 1][j];
        s4[2] += c4[2] * U.TI[m + 2][j];
        s4[3] += c4[3] * U.TI[m + 3][j];
      }
      float s = (s4[0] + s4[1]) + (s4[2] + s4[3]);
      for (; m < i; ++m) s += GW[i][m] * U.TI[m][j];
      U.TI[i][j] = ((i == j) ? 1.0f : 0.0f) - s;
    }
  }
  __syncthreads();

  // emit Tf = S*TI as bf16 hi/lo: u16 [0..4096) = hi, [4096..8192) = lo
  unsigned short* __restrict__ slotU =
      (unsigned short*)(outbuf + (size_t)b * (NROW * NCOL));
#pragma unroll
  for (int q = 0; q < 16; ++q) {
    const int idx = t + 256 * q;
    const int ii = idx >> 6;
    const int jj = idx & 63;
    const float tf = isn[ii] * U.TI[ii][jj];
    const unsigned short h = f32_to_bf16_rne(tf);
    const unsigned short l = f32_to_bf16_rne(tf - bf16_to_f32(h));
    slotU[idx] = h;
    slotU[4096 + idx] = l;
  }
}

// Kernel 2: out = Tf * X per batch, pure MFMA.  Wave w owns output rows
// [16w,16w+16); Tf fragments live in registers; X chunks (64 rows x 64
// cols) staged transposed in LDS as bf16 hi/lo (stride 68: conflict-free
// b64 frag reads, 4-way-free b64 writes).
__global__ __launch_bounds__(256) void gs_apply_kernel(const float* __restrict__ x,
                                                       float* __restrict__ outbuf)
{
  __shared__ unsigned short XTh[64][68];  // XT[c][m], hi
  __shared__ unsigned short XTl[64][68];  // lo
  __shared__ unsigned short Th[64][72];   // Tf rows, hi (16B-aligned rows)
  __shared__ unsigned short Tl[64][72];

  const int b = blockIdx.x;
  const int t = threadIdx.x;
  const int lane = t & 63;
  const int w = t >> 6;

  float* __restrict__ slot = outbuf + (size_t)b * (NROW * NCOL);
  const unsigned short* __restrict__ slotU = (const unsigned short*)slot;

  // stage Tf into LDS (coalesced u16x4 copies; id*4 == i*64 + c4)
#pragma unroll
  for (int q = 0; q < 4; ++q) {
    const int id = t + 256 * q;          // 1024 groups of 4 ushorts
    const int i = id >> 4;
    const int c4 = (id & 15) * 4;
    *(u16x4*)&Th[i][c4] = *(const u16x4*)&slotU[id * 4];
    *(u16x4*)&Tl[i][c4] = *(const u16x4*)&slotU[4096 + id * 4];
  }
  __syncthreads();   // all T ds_writes done before any wave stores to slot

  const int frow = lane & 15;
  const int fk = (lane >> 4) * 8;

  // A-operand fragments (rows 16w+frow), pinned for all chunks
  s16x8 tah[2], tal[2];
#pragma unroll
  for (int ks = 0; ks < 2; ++ks) {
    tah[ks] = *(const s16x8*)&Th[16 * w + frow][ks * 32 + fk];
    tal[ks] = *(const s16x8*)&Tl[16 * w + frow][ks * 32 + fk];
  }

  const float* __restrict__ X = x + (size_t)b * (NROW * NCOL);
  const int lrow4 = (t >> 4) * 4;        // 4 consecutive rows per thread
  const int lcol4 = (t & 15) * 4;        // 4 cols

  for (int ch = 0; ch < 8; ++ch) {
    __syncthreads();                     // protect XT from prev-chunk readers
    // stage XT chunk with register 4x4 micro-transpose -> b64 LDS writes
    float vr[4][4];
#pragma unroll
    for (int p = 0; p < 4; ++p) {
      const f32x4 v = *(const f32x4*)(X + (size_t)(lrow4 + p) * NCOL + ch * 64 + lcol4);
      vr[p][0] = v[0]; vr[p][1] = v[1]; vr[p][2] = v[2]; vr[p][3] = v[3];
    }
#pragma unroll
    for (int jj = 0; jj < 4; ++jj) {
      u16x4 hv, lv;
#pragma unroll
      for (int p = 0; p < 4; ++p) {
        const float f = vr[p][jj];
        const unsigned short h = f32_to_bf16_rne(f);
        hv[p] = h;
        lv[p] = f32_to_bf16_rne(f - bf16_to_f32(h));
      }
      *(u16x4*)&XTh[lcol4 + jj][lrow4] = hv;
      *(u16x4*)&XTl[lcol4 + jj][lrow4] = lv;
    }
    __syncthreads();

    f32x4 acc[4];
#pragma unroll
    for (int j = 0; j < 4; ++j) { acc[j][0] = 0.f; acc[j][1] = 0.f; acc[j][2] = 0.f; acc[j][3] = 0.f; }

#pragma unroll
    for (int ks = 0; ks < 2; ++ks) {
      const int kc = ks * 32 + fk;
#pragma unroll
      for (int ct = 0; ct < 4; ++ct) {
        const s16x8 xbh = ld8(&XTh[ct * 16 + frow][kc]);
        const s16x8 xbl = ld8(&XTl[ct * 16 + frow][kc]);
        acc[ct] = __builtin_amdgcn_mfma_f32_16x16x32_bf16(tah[ks], xbh, acc[ct], 0, 0, 0);
        acc[ct] = __builtin_amdgcn_mfma_f32_16x16x32_bf16(tah[ks], xbl, acc[ct], 0, 0, 0);
        acc[ct] = __builtin_amdgcn_mfma_f32_16x16x32_bf16(tal[ks], xbh, acc[ct], 0, 0, 0);
      }
    }

    const int drow = (lane >> 4) * 4;
    const int dcol = lane & 15;
#pragma unroll
    for (int ct = 0; ct < 4; ++ct)
#pragma unroll
      for (int rr = 0; rr < 4; ++rr)
        slot[(size_t)(16 * w + drow + rr) * NCOL + ch * 64 + ct * 16 + dcol] = acc[ct][rr];
  }
}

extern "C" void kernel_launch(void* const* d_in, const int* in_sizes, int n_in,
                              void* d_out, int out_size, void* d_ws, size_t ws_size,
                              hipStream_t stream) {
  const float* x = (const float*)d_in[0];
  float* out = (float*)d_out;
  gs_gram_kernel<<<NBATCH, 256, 0, stream>>>(x, out);
  gs_apply_kernel<<<NBATCH, 256, 0, stream>>>(x, out);
}

// Round 7
// 103.375 us; speedup vs baseline: 6.6829x; 1.6156x over previous
//
#include <hip/hip_runtime.h>
#include <cmath>

typedef __attribute__((ext_vector_type(4))) float f32x4;
typedef __attribute__((ext_vector_type(8))) short s16x8;
typedef __attribute__((ext_vector_type(4))) short s16x4;
typedef __attribute__((ext_vector_type(4))) unsigned short u16x4;

static constexpr int NROW = 64;     // K
static constexpr int NCOL = 512;    // L
static constexpr int NBATCH = 1024; // 32*32
static constexpr int SLOT = NROW * NCOL;   // floats per batch slot (128 KB)
static constexpr int GOFF = 16384;         // G region: floats [16384, 20480)

__device__ inline unsigned short f32_to_bf16_rne(float f) {
  unsigned u = __builtin_bit_cast(unsigned, f);
  unsigned r = (u + 0x7FFFu + ((u >> 16) & 1u)) >> 16;
  return (unsigned short)r;
}
__device__ inline float bf16_to_f32(unsigned short h) {
  unsigned u = ((unsigned)h) << 16;
  return __builtin_bit_cast(float, u);
}

// 8B-aligned s16x8 load (rows of XT are only 8B-aligned at stride 68)
__device__ inline s16x8 ld8(const unsigned short* p) {
  const s16x4 a = *(const s16x4*)(p);
  const s16x4 b = *(const s16x4*)(p + 4);
  s16x8 r;
  r[0]=a[0]; r[1]=a[1]; r[2]=a[2]; r[3]=a[3];
  r[4]=b[0]; r[5]=b[1]; r[6]=b[2]; r[7]=b[3];
  return r;
}

// Kernel 1: per-batch G = X X^T via bf16 hi/lo MFMA.  No serial code, no
// G in LDS: accumulators store straight to the batch slot's G region.
__global__ __launch_bounds__(256) void gs_gram_kernel(const float* __restrict__ x,
                                                      float* __restrict__ outbuf)
{
  __shared__ unsigned short Hs[64][72];
  __shared__ unsigned short Ls[64][72];

  const int b = blockIdx.x;
  const int t = threadIdx.x;
  const int lane = t & 63;
  const int w = t >> 6;

  const float* __restrict__ X = x + (size_t)b * SLOT;

  f32x4 acc[4];
#pragma unroll
  for (int j = 0; j < 4; ++j) { acc[j][0] = 0.f; acc[j][1] = 0.f; acc[j][2] = 0.f; acc[j][3] = 0.f; }

  const int lrow = t >> 4;               // 0..15
  const int lcol = (t & 15) * 4;
  const int frow = lane & 15;
  const int fk   = (lane >> 4) * 8;

  for (int ch = 0; ch < 8; ++ch) {
    __syncthreads();
#pragma unroll
    for (int p = 0; p < 4; ++p) {
      const int r = lrow + 16 * p;
      const f32x4 v = *(const f32x4*)(X + (size_t)r * NCOL + ch * 64 + lcol);
      u16x4 hv, lv;
#pragma unroll
      for (int j = 0; j < 4; ++j) {
        const float f = v[j];
        const unsigned short h = f32_to_bf16_rne(f);
        const unsigned short l = f32_to_bf16_rne(f - bf16_to_f32(h));
        hv[j] = h; lv[j] = l;
      }
      *(u16x4*)&Hs[r][lcol] = hv;
      *(u16x4*)&Ls[r][lcol] = lv;
    }
    __syncthreads();
#pragma unroll
    for (int s = 0; s < 2; ++s) {
      const int kc = s * 32 + fk;
      const s16x8 ha = *(const s16x8*)&Hs[16 * w + frow][kc];
      const s16x8 la = *(const s16x8*)&Ls[16 * w + frow][kc];
#pragma unroll
      for (int bt = 0; bt < 4; ++bt) {
        const s16x8 hb = *(const s16x8*)&Hs[16 * bt + frow][kc];
        const s16x8 lb = *(const s16x8*)&Ls[16 * bt + frow][kc];
        acc[bt] = __builtin_amdgcn_mfma_f32_16x16x32_bf16(ha, hb, acc[bt], 0, 0, 0);
        acc[bt] = __builtin_amdgcn_mfma_f32_16x16x32_bf16(ha, lb, acc[bt], 0, 0, 0);
        acc[bt] = __builtin_amdgcn_mfma_f32_16x16x32_bf16(la, hb, acc[bt], 0, 0, 0);
      }
    }
  }

  // C/D layout: col = lane&15, row = (lane>>4)*4 + reg
  float* __restrict__ Gs = outbuf + (size_t)b * SLOT + GOFF;
  const int drow = (lane >> 4) * 4;
  const int dcol = lane & 15;
#pragma unroll
  for (int bt = 0; bt < 4; ++bt)
#pragma unroll
    for (int rr = 0; rr < 4; ++rr)
      Gs[(16 * w + drow + rr) * 64 + 16 * bt + dcol] = acc[bt][rr];
}

// Kernel 2: one wave per batch.  Lane i holds W-row i in registers; the
// LDL recurrence builds the scaled coefficient matrix Cs in LDS (column k
// written at step k; row k read back uniformly).  Then the triangular
// inverse runs with lane j owning COLUMN j entirely in registers (no LDS
// round-trips).  Emits Tf = S*(I+C)^{-1} hi/lo-packed as u32.
__global__ __launch_bounds__(64) void gs_solve_kernel(float* __restrict__ outbuf)
{
  __shared__ float Cs[64][68];
  __shared__ float ISN[64];

  const int b = blockIdx.x;
  const int j = threadIdx.x;             // lane = row (LDL) / column (TI)
  float* __restrict__ slot = outbuf + (size_t)b * SLOT;
  const float* __restrict__ Gs = slot + GOFF;

  // W-row j of G into registers
  float wr[64];
#pragma unroll
  for (int c = 0; c < 16; ++c) {
    const f32x4 v = *(const f32x4*)(Gs + j * 64 + 4 * c);
    wr[4 * c + 0] = v[0]; wr[4 * c + 1] = v[1]; wr[4 * c + 2] = v[2]; wr[4 * c + 3] = v[3];
  }

  // LDL: W[i][k] = G[i][k] - sum_{m<k} Cs[k][m]*W[i][m], Cs[i][k]=W[i][k]/n_k
  {
    const float nk = __shfl(wr[0], 0);
    const float inv = 1.0f / nk;
    Cs[j][0] = wr[0] * inv;
    if (j == 0) ISN[0] = sqrtf(inv);
  }
#pragma unroll
  for (int k = 1; k < 64; ++k) {
    float a0 = 0.f, a1 = 0.f, a2 = 0.f, a3 = 0.f;
    const int K4 = k >> 2;
#pragma unroll
    for (int m4 = 0; m4 < K4; ++m4) {
      const f32x4 c4 = *(const f32x4*)&Cs[k][4 * m4];   // uniform broadcast
      a0 += c4[0] * wr[4 * m4 + 0];
      a1 += c4[1] * wr[4 * m4 + 1];
      a2 += c4[2] * wr[4 * m4 + 2];
      a3 += c4[3] * wr[4 * m4 + 3];
    }
#pragma unroll
    for (int m = 4 * K4; m < k; ++m) a0 += Cs[k][m] * wr[m];
    wr[k] -= (a0 + a1) + (a2 + a3);
    const float nk = __shfl(wr[k], k);
    const float inv = 1.0f / nk;
    Cs[j][k] = wr[k] * inv;
    if (j == 0) ISN[k] = sqrtf(inv);
  }

  // TI: lane j owns column j in registers.  ti[i] = d(i,j) - sum Cs[i][m]*ti[m]
  float ti[64];
  ti[0] = (j == 0) ? 1.0f : 0.0f;
#pragma unroll
  for (int i = 1; i < 64; ++i) {
    float a0 = 0.f, a1 = 0.f, a2 = 0.f, a3 = 0.f;
    const int I4 = i >> 2;
#pragma unroll
    for (int m4 = 0; m4 < I4; ++m4) {
      const f32x4 c4 = *(const f32x4*)&Cs[i][4 * m4];   // uniform broadcast
      a0 += c4[0] * ti[4 * m4 + 0];
      a1 += c4[1] * ti[4 * m4 + 1];
      a2 += c4[2] * ti[4 * m4 + 2];
      a3 += c4[3] * ti[4 * m4 + 3];
    }
#pragma unroll
    for (int m = 4 * I4; m < i; ++m) a0 += Cs[i][m] * ti[m];
    ti[i] = ((i == j) ? 1.0f : 0.0f) - ((a0 + a1) + (a2 + a3));
  }

  // emit Tf[i][j] = ISN[i]*ti[i], hi/lo bf16 packed in one u32, coalesced
  unsigned int* __restrict__ slotT = (unsigned int*)slot;
#pragma unroll
  for (int i = 0; i < 64; ++i) {
    const float tf = ISN[i] * ti[i];
    const unsigned short h = f32_to_bf16_rne(tf);
    const unsigned short l = f32_to_bf16_rne(tf - bf16_to_f32(h));
    slotT[i * 64 + j] = (unsigned)h | ((unsigned)l << 16);
  }
}

// Kernel 3: out = Tf * X per batch, pure MFMA (unchanged structure; T now
// unpacked from u32 hi/lo pairs).
__global__ __launch_bounds__(256) void gs_apply_kernel(const float* __restrict__ x,
                                                       float* __restrict__ outbuf)
{
  __shared__ unsigned short XTh[64][68];
  __shared__ unsigned short XTl[64][68];
  __shared__ unsigned short Th[64][72];
  __shared__ unsigned short Tl[64][72];

  const int b = blockIdx.x;
  const int t = threadIdx.x;
  const int lane = t & 63;
  const int w = t >> 6;

  float* __restrict__ slot = outbuf + (size_t)b * SLOT;
  const unsigned int* __restrict__ slotT = (const unsigned int*)slot;

  // stage Tf into LDS (u32 -> hi/lo u16) BEFORE any output store
#pragma unroll
  for (int q = 0; q < 16; ++q) {
    const int id = t + 256 * q;          // id = i*64 + c
    const int i = id >> 6;
    const int c = id & 63;
    const unsigned v = slotT[id];
    Th[i][c] = (unsigned short)(v & 0xFFFFu);
    Tl[i][c] = (unsigned short)(v >> 16);
  }
  __syncthreads();   // all T staged before any wave stores to slot

  const int frow = lane & 15;
  const int fk = (lane >> 4) * 8;

  s16x8 tah[2], tal[2];
#pragma unroll
  for (int ks = 0; ks < 2; ++ks) {
    tah[ks] = *(const s16x8*)&Th[16 * w + frow][ks * 32 + fk];
    tal[ks] = *(const s16x8*)&Tl[16 * w + frow][ks * 32 + fk];
  }

  const float* __restrict__ X = x + (size_t)b * SLOT;
  const int lrow4 = (t >> 4) * 4;
  const int lcol4 = (t & 15) * 4;

  for (int ch = 0; ch < 8; ++ch) {
    __syncthreads();
    float vr[4][4];
#pragma unroll
    for (int p = 0; p < 4; ++p) {
      const f32x4 v = *(const f32x4*)(X + (size_t)(lrow4 + p) * NCOL + ch * 64 + lcol4);
      vr[p][0] = v[0]; vr[p][1] = v[1]; vr[p][2] = v[2]; vr[p][3] = v[3];
    }
#pragma unroll
    for (int jj = 0; jj < 4; ++jj) {
      u16x4 hv, lv;
#pragma unroll
      for (int p = 0; p < 4; ++p) {
        const float f = vr[p][jj];
        const unsigned short h = f32_to_bf16_rne(f);
        hv[p] = h;
        lv[p] = f32_to_bf16_rne(f - bf16_to_f32(h));
      }
      *(u16x4*)&XTh[lcol4 + jj][lrow4] = hv;
      *(u16x4*)&XTl[lcol4 + jj][lrow4] = lv;
    }
    __syncthreads();

    f32x4 acc[4];
#pragma unroll
    for (int q = 0; q < 4; ++q) { acc[q][0] = 0.f; acc[q][1] = 0.f; acc[q][2] = 0.f; acc[q][3] = 0.f; }

#pragma unroll
    for (int ks = 0; ks < 2; ++ks) {
      const int kc = ks * 32 + fk;
#pragma unroll
      for (int ct = 0; ct < 4; ++ct) {
        const s16x8 xbh = ld8(&XTh[ct * 16 + frow][kc]);
        const s16x8 xbl = ld8(&XTl[ct * 16 + frow][kc]);
        acc[ct] = __builtin_amdgcn_mfma_f32_16x16x32_bf16(tah[ks], xbh, acc[ct], 0, 0, 0);
        acc[ct] = __builtin_amdgcn_mfma_f32_16x16x32_bf16(tah[ks], xbl, acc[ct], 0, 0, 0);
        acc[ct] = __builtin_amdgcn_mfma_f32_16x16x32_bf16(tal[ks], xbh, acc[ct], 0, 0, 0);
      }
    }

    const int drow = (lane >> 4) * 4;
    const int dcol = lane & 15;
#pragma unroll
    for (int ct = 0; ct < 4; ++ct)
#pragma unroll
      for (int rr = 0; rr < 4; ++rr)
        slot[(size_t)(16 * w + drow + rr) * NCOL + ch * 64 + ct * 16 + dcol] = acc[ct][rr];
  }
}

extern "C" void kernel_launch(void* const* d_in, const int* in_sizes, int n_in,
                              void* d_out, int out_size, void* d_ws, size_t ws_size,
                              hipStream_t stream) {
  const float* x = (const float*)d_in[0];
  float* out = (float*)d_out;
  gs_gram_kernel<<<NBATCH, 256, 0, stream>>>(x, out);
  gs_solve_kernel<<<NBATCH, 64, 0, stream>>>(out);
  gs_apply_kernel<<<NBATCH, 256, 0, stream>>>(x, out);
}